// Round 1
// baseline (750.691 us; speedup 1.0000x reference)
//
#include <hip/hip_runtime.h>
#include <math.h>

// FractionalDilationR2: out[b,c,y,x] = max_{dy,dx in [-5,5]} u[b,c,y+dy,x+dx] - k[c,dy+5,dx+5]
// k_c = nu * rho^e * exp(-e * sum_j p[c,j] B_j(theta)),  e = 2a/(2a-1), a = 0.65 (e = 13/3).
//
// Exact pruning: center tap has k=0, so acc >= u[p] >= tileMin. Any tap with
// k >= tileMax - tileMin (valid values only) can never exceed acc -> drop it.
// Per dx column we keep a contiguous [lo,hi] dy-hull of live taps (conservative,
// always correct; full range when delta is large).
//
// R1 change: register-resident column reuse. For each dx, the 8 vertical outputs
// over all 11 dy taps touch only 18 distinct tile values -> load them ONCE into
// registers (static indexing only), then run dy fully in regs. LDS reads drop
// 968 -> 198 per thread-tile (old kernel sat at the ~69 TB/s LDS roofline).
// dy taps are paired so fmaxf(acc, fmaxf(t0,t1)) can fuse to v_max3_f32
// (1.5 VALU ops/tap). Tap set identical to previous version; fmax reordering is
// exact, so output is bitwise unchanged.

#define RR 5
#define KS 11
#define NTAPS (KS * KS)     // 121
#define HDIM 512
#define WDIM 512
#define NCH 32
#define TX 64               // output tile width (= lanes in x)
#define TY 32               // output tile height per iteration
#define VPT 8               // vertical outputs per thread
#define COLN (KS + VPT - 1) // 18 column values per dx
#define TH (TY + 2 * RR)    // 42 tile rows in LDS
#define TW (TX + 2 * RR)    // 74 tile cols
#define PITCH 76            // padded LDS pitch (floats)
#define NEGF (-1e30f)

// ---- pre-kernel: build the 32x121 kernel table in double, once per launch ----
__global__ void build_ktab_kernel(const float* __restrict__ finsler,
                                  float* __restrict__ ktab) {
    const int c = blockIdx.x;          // 0..31
    const int t = threadIdx.x;         // 0..127
    if (t >= NTAPS) return;
    const int dy = t / KS - RR;
    const int dx = t % KS - RR;
    const double rho = sqrt((double)(dx * dx + dy * dy));
    const double th  = atan2((double)dy, (double)dx);
    const float* pc = finsler + c * 6;
    const double g =
        (double)pc[0] * cos(th)       + (double)pc[1] * sin(th) +
        (double)pc[2] * cos(2.0 * th) + (double)pc[3] * sin(2.0 * th) +
        (double)pc[4] * cos(3.0 * th) + (double)pc[5] * sin(3.0 * th);
    const double e  = 2.0 * 0.65 / (2.0 * 0.65 - 1.0);     // 13/3
    const double nu = (2.0 * 0.65 - 1.0) * pow(2.0 * 0.65, -e);
    const double kvd = (rho == 0.0) ? 0.0 : nu * pow(rho, e) * exp(-e * g);
    ktab[c * NTAPS + t] = (float)kvd;
}

__global__ __launch_bounds__(256, 4) void frac_dilation_kernel(
    const float* __restrict__ u,
    const float* __restrict__ ktab,    // [32,121] precomputed
    float* __restrict__ out)
{
    __shared__ float klds[NTAPS];
    __shared__ float tile[TH * PITCH];
    __shared__ float wmaxs[4], wmins[4];
    __shared__ int   lohi_lds[KS];

    const int tx  = threadIdx.x;          // 0..63
    const int ty  = threadIdx.y;          // 0..3
    const int tid = ty * 64 + tx;
    const int p   = blockIdx.y;           // plane index b*32+c
    const int c   = p & (NCH - 1);
    const int ox  = blockIdx.x * TX;

    if (tid < NTAPS) klds[tid] = ktab[c * NTAPS + tid];
    // visible after the first __syncthreads below

    const float* uplane = u   + (size_t)p * (HDIM * WDIM);
    float*       oplane = out + (size_t)p * (HDIM * WDIM);
    const int y0 = ty * VPT;              // this thread's first output row (local)

#pragma unroll 1
    for (int itY = 0; itY < HDIM / TY; ++itY) {
        const int oy = itY * TY;

        __syncthreads();   // A: previous compute must finish before tile reload

        // ---- stage tile + halo, tracking valid-value min/max ----
        float vmax = -3.0e38f, vmin = 3.0e38f;
#pragma unroll 1
        for (int r = ty; r < TH; r += 4) {
            const int gy = oy + r - RR;
            const bool yok = (gy >= 0) & (gy < HDIM);
#pragma unroll 1
            for (int cc = tx; cc < TW; cc += 64) {
                const int gx = ox + cc - RR;
                float v = NEGF;
                if (yok && gx >= 0 && gx < WDIM) {
                    v = uplane[gy * WDIM + gx];
                    vmax = fmaxf(vmax, v);
                    vmin = fminf(vmin, v);
                }
                tile[r * PITCH + cc] = v;
            }
        }
        // wave-level reduce (width 64)
#pragma unroll
        for (int m = 1; m < 64; m <<= 1) {
            vmax = fmaxf(vmax, __shfl_xor(vmax, m, 64));
            vmin = fminf(vmin, __shfl_xor(vmin, m, 64));
        }
        if (tx == 0) { wmaxs[ty] = vmax; wmins[ty] = vmin; }
        __syncthreads();   // B: tile + wave partials visible

        const float tmax = fmaxf(fmaxf(wmaxs[0], wmaxs[1]), fmaxf(wmaxs[2], wmaxs[3]));
        const float tmin = fminf(fminf(wmins[0], wmins[1]), fminf(wmins[2], wmins[3]));
        const float delta = tmax - tmin;   // >= 0; center tap k=0 always live

        if (tid < KS) {                    // one thread per dx: contiguous dy hull
            int lo = 1, hi = 0;
#pragma unroll
            for (int dy = 0; dy < KS; ++dy) {
                if (klds[dy * KS + tid] <= delta) { if (lo > hi) lo = dy; hi = dy; }
            }
            lohi_lds[tid] = lo | (hi << 16);
        }
        __syncthreads();   // C: hulls visible

        // ---- pruned max-plus accumulation, register-resident columns ----
        float acc[VPT];
#pragma unroll
        for (int i = 0; i < VPT; ++i) acc[i] = NEGF;

#pragma unroll 1
        for (int dx = 0; dx < KS; ++dx) {
            const int lh = __builtin_amdgcn_readfirstlane(lohi_lds[dx]);
            const int lo = lh & 0xffff;
            const int hi = lh >> 16;
            if (lo > hi) continue;         // whole column pruned (uniform branch)

            // load the 18 column values for this dx once (static reg indexing)
            float col[COLN];
            {
                const float* cp = &tile[y0 * PITCH + tx + dx];
#pragma unroll
                for (int r = 0; r < COLN; ++r) col[r] = cp[r * PITCH];
            }
            const float* kcol = &klds[dx];

            // dy taps in pairs -> v_max3_f32; [lo,hi] guards are wave-uniform.
#pragma unroll
            for (int dyp = 0; dyp < (KS + 1) / 2; ++dyp) {
                const int dy0 = 2 * dyp;
                const int dy1 = dy0 + 1;
                const bool l0 = (dy0 >= lo) & (dy0 <= hi);
                const bool l1 = (dy1 < KS) && (dy1 >= lo) && (dy1 <= hi);
                if (l0 & l1) {
                    const float kv0 = kcol[dy0 * KS];
                    const float kv1 = kcol[dy1 * KS];
#pragma unroll
                    for (int i = 0; i < VPT; ++i)
                        acc[i] = fmaxf(acc[i],
                                       fmaxf(col[dy0 + i] - kv0,
                                             col[dy1 + i] - kv1));
                } else if (l0) {
                    const float kv0 = kcol[dy0 * KS];
#pragma unroll
                    for (int i = 0; i < VPT; ++i)
                        acc[i] = fmaxf(acc[i], col[dy0 + i] - kv0);
                } else if (l1) {
                    const float kv1 = kcol[dy1 * KS];
#pragma unroll
                    for (int i = 0; i < VPT; ++i)
                        acc[i] = fmaxf(acc[i], col[dy1 + i] - kv1);
                }
            }
        }

        // ---- store ----
#pragma unroll
        for (int i = 0; i < VPT; ++i)
            oplane[(oy + y0 + i) * WDIM + ox + tx] = acc[i];
    }
}

extern "C" void kernel_launch(void* const* d_in, const int* in_sizes, int n_in,
                              void* d_out, int out_size, void* d_ws, size_t ws_size,
                              hipStream_t stream) {
    const float* u  = (const float*)d_in[0];   // (8,32,512,512) fp32
    const float* fp = (const float*)d_in[1];   // (32,6) fp32
    float* out  = (float*)d_out;
    float* ktab = (float*)d_ws;                // 32*121 floats = 15.5 KB scratch

    build_ktab_kernel<<<dim3(NCH), dim3(128), 0, stream>>>(fp, ktab);

    dim3 grid(WDIM / TX, 8 * NCH);   // 8 x-strips, 256 planes
    dim3 block(64, 4);
    frac_dilation_kernel<<<grid, block, 0, stream>>>(u, ktab, out);
}

// Round 2
// 662.315 us; speedup vs baseline: 1.1334x; 1.1334x over previous
//
#include <hip/hip_runtime.h>
#include <math.h>

// FractionalDilationR2: out[b,c,y,x] = max_{dy,dx in [-5,5]} u[b,c,y+dy,x+dx] - k[c,dy+5,dx+5]
// k_c = nu * rho^e * exp(-e * sum_j p[c,j] B_j(theta)),  e = 2a/(2a-1), a = 0.65 (e = 13/3).
//
// Exact pruning: center tap has k=0, so acc >= u[p] >= tileMin. Any tap with
// k >= tileMax - tileMin (valid values only) can never exceed acc -> drop it.
// Per dx column we keep a contiguous [lo,hi] dy-hull of live taps.
//
// R2 change (T14 async-STAGE split): R1 showed the kernel is NOT LDS-BW-bound
// (5x fewer LDS reads -> time +5%, VALUBusy 79->62%). The missing time is
// global-load latency exposed in the serial stage->barrier->compute structure.
// Fix: ISSUE next tile's global loads into registers BEFORE the compute phase,
// WRITE regs->LDS after the post-compute barrier. Inner compute loop reverted
// to the proven R0 form to isolate this one variable. Valid-min tracking moves
// to the write phase (NEGF-exclusion cndmask); tracking at issue time would
// force an immediate vmcnt wait and defeat the split.

#define RR 5
#define KS 11
#define NTAPS (KS * KS)     // 121
#define HDIM 512
#define WDIM 512
#define NCH 32
#define TX 64               // output tile width (= lanes in x)
#define TY 32               // output tile height per iteration
#define VPT 8               // vertical outputs per thread
#define TH (TY + 2 * RR)    // 42 tile rows in LDS
#define TW (TX + 2 * RR)    // 74 tile cols
#define PITCH 76            // padded LDS pitch (floats)
#define NJR 11              // max staging row-iters per thread (ceil(42/4) + 1 slack)
#define NEGF (-1e30f)

// ---- pre-kernel: build the 32x121 kernel table in double, once per launch ----
__global__ void build_ktab_kernel(const float* __restrict__ finsler,
                                  float* __restrict__ ktab) {
    const int c = blockIdx.x;          // 0..31
    const int t = threadIdx.x;         // 0..127
    if (t >= NTAPS) return;
    const int dy = t / KS - RR;
    const int dx = t % KS - RR;
    const double rho = sqrt((double)(dx * dx + dy * dy));
    const double th  = atan2((double)dy, (double)dx);
    const float* pc = finsler + c * 6;
    const double g =
        (double)pc[0] * cos(th)       + (double)pc[1] * sin(th) +
        (double)pc[2] * cos(2.0 * th) + (double)pc[3] * sin(2.0 * th) +
        (double)pc[4] * cos(3.0 * th) + (double)pc[5] * sin(3.0 * th);
    const double e  = 2.0 * 0.65 / (2.0 * 0.65 - 1.0);     // 13/3
    const double nu = (2.0 * 0.65 - 1.0) * pow(2.0 * 0.65, -e);
    const double kvd = (rho == 0.0) ? 0.0 : nu * pow(rho, e) * exp(-e * g);
    ktab[c * NTAPS + t] = (float)kvd;
}

__global__ __launch_bounds__(256, 4) void frac_dilation_kernel(
    const float* __restrict__ u,
    const float* __restrict__ ktab,    // [32,121] precomputed
    float* __restrict__ out)
{
    __shared__ float klds[NTAPS];
    __shared__ float tile[TH * PITCH];
    __shared__ float wmaxs[4], wmins[4];
    __shared__ int   lohi_lds[KS];

    const int tx  = threadIdx.x;          // 0..63
    const int ty  = threadIdx.y;          // 0..3
    const int tid = ty * 64 + tx;
    const int p   = blockIdx.y;           // plane index b*32+c
    const int c   = p & (NCH - 1);
    const int ox  = blockIdx.x * TX;

    if (tid < NTAPS) klds[tid] = ktab[c * NTAPS + tid];
    // visible after the first __syncthreads below

    const float* uplane = u   + (size_t)p * (HDIM * WDIM);
    float*       oplane = out + (size_t)p * (HDIM * WDIM);
    const int y0 = ty * VPT;              // this thread's first output row (local)

    // staging registers: column cc=tx (all lanes) and cc=tx+64 (lanes tx<10)
    float sreg0[NJR], sreg1[NJR];

    // ---- ISSUE: launch global loads for tile itY into sreg (no waits) ----
    auto issue_tile = [&](int itY) {
        const int oyl = itY * TY;
#pragma unroll
        for (int jr = 0; jr < NJR; ++jr) {
            const int r = ty + 4 * jr;       // wave-uniform row index
            float v0 = NEGF, v1 = NEGF;
            if (r < TH) {                    // uniform branch (ty uniform per wave)
                const int gy = oyl + r - RR;
                const bool yok = (gy >= 0) & (gy < HDIM);
                {
                    const int gx = ox + tx - RR;
                    if (yok && gx >= 0 && gx < WDIM)
                        v0 = uplane[gy * WDIM + gx];
                }
                if (tx < TW - 64) {          // second column strip, lanes 0..9
                    const int gx = ox + tx + 64 - RR;
                    if (yok && gx < WDIM)
                        v1 = uplane[gy * WDIM + gx];
                }
            }
            sreg0[jr] = v0;
            sreg1[jr] = v1;
        }
    };

    issue_tile(0);   // prologue: loads for first tile in flight

#pragma unroll 1
    for (int itY = 0; itY < HDIM / TY; ++itY) {
        const int oy = itY * TY;

        __syncthreads();   // A: previous compute must finish before tile overwrite

        // ---- WRITE: regs -> LDS, tracking valid-value min/max ----
        float vmax = -3.0e38f, vmin = 3.0e38f;
#pragma unroll
        for (int jr = 0; jr < NJR; ++jr) {
            const int r = ty + 4 * jr;
            if (r < TH) {
                {
                    const float v = sreg0[jr];
                    tile[r * PITCH + tx] = v;
                    vmax = fmaxf(vmax, v);                       // NEGF never wins
                    vmin = fminf(vmin, (v < -1e29f) ? 3.0e38f : v); // exclude padding
                }
                if (tx < TW - 64) {
                    const float v = sreg1[jr];
                    tile[r * PITCH + tx + 64] = v;
                    vmax = fmaxf(vmax, v);
                    vmin = fminf(vmin, (v < -1e29f) ? 3.0e38f : v);
                }
            }
        }
        // wave-level reduce (width 64)
#pragma unroll
        for (int m = 1; m < 64; m <<= 1) {
            vmax = fmaxf(vmax, __shfl_xor(vmax, m, 64));
            vmin = fminf(vmin, __shfl_xor(vmin, m, 64));
        }
        if (tx == 0) { wmaxs[ty] = vmax; wmins[ty] = vmin; }
        __syncthreads();   // B: tile + wave partials visible

        const float tmax = fmaxf(fmaxf(wmaxs[0], wmaxs[1]), fmaxf(wmaxs[2], wmaxs[3]));
        const float tmin = fminf(fminf(wmins[0], wmins[1]), fminf(wmins[2], wmins[3]));
        const float delta = tmax - tmin;   // >= 0; center tap k=0 always live

        if (tid < KS) {                    // one thread per dx: contiguous dy hull
            int lo = 1, hi = 0;
#pragma unroll
            for (int dy = 0; dy < KS; ++dy) {
                if (klds[dy * KS + tid] <= delta) { if (lo > hi) lo = dy; hi = dy; }
            }
            lohi_lds[tid] = lo | (hi << 16);
        }
        __syncthreads();   // C: hulls visible

        // ---- issue NEXT tile's loads; latency hides under compute below ----
        if (itY + 1 < HDIM / TY) issue_tile(itY + 1);

        // ---- pruned max-plus accumulation (proven R0 inner loop) ----
        float acc[VPT];
#pragma unroll
        for (int i = 0; i < VPT; ++i) acc[i] = NEGF;

#pragma unroll
        for (int dx = 0; dx < KS; ++dx) {
            const int lh = __builtin_amdgcn_readfirstlane(lohi_lds[dx]);
            const int lo = lh & 0xffff;
            const int hi = lh >> 16;
#pragma unroll 1
            for (int dy = lo; dy <= hi; ++dy) {
                const float kvv = klds[dy * KS + dx];
                const float* cp = &tile[(y0 + dy) * PITCH + tx + dx];
#pragma unroll
                for (int i = 0; i < VPT; ++i)
                    acc[i] = fmaxf(acc[i], cp[i * PITCH] - kvv);
            }
        }

        // ---- store ----
#pragma unroll
        for (int i = 0; i < VPT; ++i)
            oplane[(oy + y0 + i) * WDIM + ox + tx] = acc[i];
    }
}

extern "C" void kernel_launch(void* const* d_in, const int* in_sizes, int n_in,
                              void* d_out, int out_size, void* d_ws, size_t ws_size,
                              hipStream_t stream) {
    const float* u  = (const float*)d_in[0];   // (8,32,512,512) fp32
    const float* fp = (const float*)d_in[1];   // (32,6) fp32
    float* out  = (float*)d_out;
    float* ktab = (float*)d_ws;                // 32*121 floats = 15.5 KB scratch

    build_ktab_kernel<<<dim3(NCH), dim3(128), 0, stream>>>(fp, ktab);

    dim3 grid(WDIM / TX, 8 * NCH);   // 8 x-strips, 256 planes
    dim3 block(64, 4);
    frac_dilation_kernel<<<grid, block, 0, stream>>>(u, ktab, out);
}

// Round 3
// 540.270 us; speedup vs baseline: 1.3895x; 1.2259x over previous
//
#include <hip/hip_runtime.h>
#include <math.h>

// FractionalDilationR2: out[b,c,y,x] = max_{dy,dx in [-5,5]} u[b,c,y+dy,x+dx] - k[c,dy+5,dx+5]
// k_c = nu * rho^e * exp(-e * sum_j p[c,j] B_j(theta)),  e = 2a/(2a-1), a = 0.65 (e = 13/3).
//
// Exact pruning: center tap has k=0, so acc >= u[p] >= tileMin. Any tap with
// k >= tileMax - tileMin (valid values only) can never exceed acc -> drop it.
// Per dx column we keep a contiguous [lo,hi] dy-hull of live taps.
//
// R2 (kept): T14 async-STAGE split — issue next tile's global loads into regs
// before the compute phase, write regs->LDS after the barrier. 438 -> 397 us.
//
// R3 change: dy-pair + max3. VALU accounting shows ~24 VALU-cyc/tap with ~1/3
// loop overhead; kernel is VALU-issue-bound (VALUBusy 82%). Process dy taps in
// pairs: shared 9-row register window w[0..8] (static indexing, full unroll),
// acc = max3(acc, w[i]-k0, w[i+1]-k1). Per pair: 9 LDS reads (vs 16),
// 24 VALU (vs 32), one iteration of loop overhead (vs two). Tap set and fmax
// semantics unchanged -> bitwise-identical output.

#define RR 5
#define KS 11
#define NTAPS (KS * KS)     // 121
#define HDIM 512
#define WDIM 512
#define NCH 32
#define TX 64               // output tile width (= lanes in x)
#define TY 32               // output tile height per iteration
#define VPT 8               // vertical outputs per thread
#define TH (TY + 2 * RR)    // 42 tile rows in LDS
#define TW (TX + 2 * RR)    // 74 tile cols
#define PITCH 76            // padded LDS pitch (floats)
#define NJR 11              // max staging row-iters per thread (ceil(42/4) + 1 slack)
#define NEGF (-1e30f)

// ---- pre-kernel: build the 32x121 kernel table in double, once per launch ----
__global__ void build_ktab_kernel(const float* __restrict__ finsler,
                                  float* __restrict__ ktab) {
    const int c = blockIdx.x;          // 0..31
    const int t = threadIdx.x;         // 0..127
    if (t >= NTAPS) return;
    const int dy = t / KS - RR;
    const int dx = t % KS - RR;
    const double rho = sqrt((double)(dx * dx + dy * dy));
    const double th  = atan2((double)dy, (double)dx);
    const float* pc = finsler + c * 6;
    const double g =
        (double)pc[0] * cos(th)       + (double)pc[1] * sin(th) +
        (double)pc[2] * cos(2.0 * th) + (double)pc[3] * sin(2.0 * th) +
        (double)pc[4] * cos(3.0 * th) + (double)pc[5] * sin(3.0 * th);
    const double e  = 2.0 * 0.65 / (2.0 * 0.65 - 1.0);     // 13/3
    const double nu = (2.0 * 0.65 - 1.0) * pow(2.0 * 0.65, -e);
    const double kvd = (rho == 0.0) ? 0.0 : nu * pow(rho, e) * exp(-e * g);
    ktab[c * NTAPS + t] = (float)kvd;
}

__global__ __launch_bounds__(256, 4) void frac_dilation_kernel(
    const float* __restrict__ u,
    const float* __restrict__ ktab,    // [32,121] precomputed
    float* __restrict__ out)
{
    __shared__ float klds[NTAPS];
    __shared__ float tile[TH * PITCH];
    __shared__ float wmaxs[4], wmins[4];
    __shared__ int   lohi_lds[KS];

    const int tx  = threadIdx.x;          // 0..63
    const int ty  = threadIdx.y;          // 0..3
    const int tid = ty * 64 + tx;
    const int p   = blockIdx.y;           // plane index b*32+c
    const int c   = p & (NCH - 1);
    const int ox  = blockIdx.x * TX;

    if (tid < NTAPS) klds[tid] = ktab[c * NTAPS + tid];
    // visible after the first __syncthreads below

    const float* uplane = u   + (size_t)p * (HDIM * WDIM);
    float*       oplane = out + (size_t)p * (HDIM * WDIM);
    const int y0 = ty * VPT;              // this thread's first output row (local)

    // staging registers: column cc=tx (all lanes) and cc=tx+64 (lanes tx<10)
    float sreg0[NJR], sreg1[NJR];

    // ---- ISSUE: launch global loads for tile itY into sreg (no waits) ----
    auto issue_tile = [&](int itY) {
        const int oyl = itY * TY;
#pragma unroll
        for (int jr = 0; jr < NJR; ++jr) {
            const int r = ty + 4 * jr;       // wave-uniform row index
            float v0 = NEGF, v1 = NEGF;
            if (r < TH) {                    // uniform branch (ty uniform per wave)
                const int gy = oyl + r - RR;
                const bool yok = (gy >= 0) & (gy < HDIM);
                {
                    const int gx = ox + tx - RR;
                    if (yok && gx >= 0 && gx < WDIM)
                        v0 = uplane[gy * WDIM + gx];
                }
                if (tx < TW - 64) {          // second column strip, lanes 0..9
                    const int gx = ox + tx + 64 - RR;
                    if (yok && gx < WDIM)
                        v1 = uplane[gy * WDIM + gx];
                }
            }
            sreg0[jr] = v0;
            sreg1[jr] = v1;
        }
    };

    issue_tile(0);   // prologue: loads for first tile in flight

#pragma unroll 1
    for (int itY = 0; itY < HDIM / TY; ++itY) {
        const int oy = itY * TY;

        __syncthreads();   // A: previous compute must finish before tile overwrite

        // ---- WRITE: regs -> LDS, tracking valid-value min/max ----
        float vmax = -3.0e38f, vmin = 3.0e38f;
#pragma unroll
        for (int jr = 0; jr < NJR; ++jr) {
            const int r = ty + 4 * jr;
            if (r < TH) {
                {
                    const float v = sreg0[jr];
                    tile[r * PITCH + tx] = v;
                    vmax = fmaxf(vmax, v);                       // NEGF never wins
                    vmin = fminf(vmin, (v < -1e29f) ? 3.0e38f : v); // exclude padding
                }
                if (tx < TW - 64) {
                    const float v = sreg1[jr];
                    tile[r * PITCH + tx + 64] = v;
                    vmax = fmaxf(vmax, v);
                    vmin = fminf(vmin, (v < -1e29f) ? 3.0e38f : v);
                }
            }
        }
        // wave-level reduce (width 64)
#pragma unroll
        for (int m = 1; m < 64; m <<= 1) {
            vmax = fmaxf(vmax, __shfl_xor(vmax, m, 64));
            vmin = fminf(vmin, __shfl_xor(vmin, m, 64));
        }
        if (tx == 0) { wmaxs[ty] = vmax; wmins[ty] = vmin; }
        __syncthreads();   // B: tile + wave partials visible

        const float tmax = fmaxf(fmaxf(wmaxs[0], wmaxs[1]), fmaxf(wmaxs[2], wmaxs[3]));
        const float tmin = fminf(fminf(wmins[0], wmins[1]), fminf(wmins[2], wmins[3]));
        const float delta = tmax - tmin;   // >= 0; center tap k=0 always live

        if (tid < KS) {                    // one thread per dx: contiguous dy hull
            int lo = 1, hi = 0;
#pragma unroll
            for (int dy = 0; dy < KS; ++dy) {
                if (klds[dy * KS + tid] <= delta) { if (lo > hi) lo = dy; hi = dy; }
            }
            lohi_lds[tid] = lo | (hi << 16);
        }
        __syncthreads();   // C: hulls visible

        // ---- issue NEXT tile's loads; latency hides under compute below ----
        if (itY + 1 < HDIM / TY) issue_tile(itY + 1);

        // ---- pruned max-plus accumulation, dy pairs + max3 ----
        float acc[VPT];
#pragma unroll
        for (int i = 0; i < VPT; ++i) acc[i] = NEGF;

#pragma unroll
        for (int dx = 0; dx < KS; ++dx) {
            const int lh = __builtin_amdgcn_readfirstlane(lohi_lds[dx]);
            const int lo = lh & 0xffff;
            const int hi = lh >> 16;

            int dy = lo;
#pragma unroll 1
            for (; dy + 1 <= hi; dy += 2) {
                const float k0 = klds[dy * KS + dx];
                const float k1 = klds[(dy + 1) * KS + dx];
                const float* cp = &tile[(y0 + dy) * PITCH + tx + dx];
                // 9-row shared window for the tap pair (static reg indexing)
                float w[VPT + 1];
#pragma unroll
                for (int r = 0; r < VPT + 1; ++r) w[r] = cp[r * PITCH];
#pragma unroll
                for (int i = 0; i < VPT; ++i)
                    acc[i] = fmaxf(acc[i],
                                   fmaxf(w[i] - k0, w[i + 1] - k1));
            }
            if (dy == hi) {                  // odd tail (wave-uniform)
                const float kvv = klds[dy * KS + dx];
                const float* cp = &tile[(y0 + dy) * PITCH + tx + dx];
#pragma unroll
                for (int i = 0; i < VPT; ++i)
                    acc[i] = fmaxf(acc[i], cp[i * PITCH] - kvv);
            }
        }

        // ---- store ----
#pragma unroll
        for (int i = 0; i < VPT; ++i)
            oplane[(oy + y0 + i) * WDIM + ox + tx] = acc[i];
    }
}

extern "C" void kernel_launch(void* const* d_in, const int* in_sizes, int n_in,
                              void* d_out, int out_size, void* d_ws, size_t ws_size,
                              hipStream_t stream) {
    const float* u  = (const float*)d_in[0];   // (8,32,512,512) fp32
    const float* fp = (const float*)d_in[1];   // (32,6) fp32
    float* out  = (float*)d_out;
    float* ktab = (float*)d_ws;                // 32*121 floats = 15.5 KB scratch

    build_ktab_kernel<<<dim3(NCH), dim3(128), 0, stream>>>(fp, ktab);

    dim3 grid(WDIM / TX, 8 * NCH);   // 8 x-strips, 256 planes
    dim3 block(64, 4);
    frac_dilation_kernel<<<grid, block, 0, stream>>>(u, ktab, out);
}

// Round 4
// 512.130 us; speedup vs baseline: 1.4658x; 1.0549x over previous
//
#include <hip/hip_runtime.h>
#include <math.h>

// FractionalDilationR2: out[b,c,y,x] = max_{dy,dx in [-5,5]} u[b,c,y+dy,x+dx] - k[c,dy+5,dx+5]
// k_c = nu * rho^e * exp(-e * sum_j p[c,j] B_j(theta)),  e = 2a/(2a-1), a = 0.65 (e = 13/3).
//
// Exact pruning: center tap has k=0, so acc >= u[p] >= tileMin. Any tap with
// k >= tileMax - tileMin (valid values only) can never exceed acc -> drop it.
// Per dx column we keep a contiguous [lo,hi] dy-hull of live taps.
//
// R2 (kept): T14 async-STAGE split — 438 -> 397 us.
// R3 (kept): dy-pair + max3, 9-row register window — 397 -> 257 us.
//   Tap math is now at the exact-formulation floor: 1 sub/candidate +
//   max3 merging 2 candidates = 1.5 VALU per (tap,output).
//
// R4 change: overhead shave. (a) ty -> scalar via readfirstlane so staging
// row indices/bounds/addresses are SALU + s-base/v-offset loads; per-lane
// x-masks hoisted out of all loops. (b) interior tiles of interior-x blocks
// (no padding possible) take a select-free min/max tracking path.
// (c) launch_bounds(256,8) as occupancy diagnostic (VGPR=40 << 64, regalloc
// unconstrained). Loads/values/tap set bit-identical to R3.

#define RR 5
#define KS 11
#define NTAPS (KS * KS)     // 121
#define HDIM 512
#define WDIM 512
#define NCH 32
#define TX 64               // output tile width (= lanes in x)
#define TY 32               // output tile height per iteration
#define VPT 8               // vertical outputs per thread
#define TH (TY + 2 * RR)    // 42 tile rows in LDS
#define TW (TX + 2 * RR)    // 74 tile cols
#define PITCH 76            // padded LDS pitch (floats)
#define NJR 11              // staging row-iters per thread (covers r = ty+4*jr < 42)
#define NEGF (-1e30f)

// ---- pre-kernel: build the 32x121 kernel table in double, once per launch ----
__global__ void build_ktab_kernel(const float* __restrict__ finsler,
                                  float* __restrict__ ktab) {
    const int c = blockIdx.x;          // 0..31
    const int t = threadIdx.x;         // 0..127
    if (t >= NTAPS) return;
    const int dy = t / KS - RR;
    const int dx = t % KS - RR;
    const double rho = sqrt((double)(dx * dx + dy * dy));
    const double th  = atan2((double)dy, (double)dx);
    const float* pc = finsler + c * 6;
    const double g =
        (double)pc[0] * cos(th)       + (double)pc[1] * sin(th) +
        (double)pc[2] * cos(2.0 * th) + (double)pc[3] * sin(2.0 * th) +
        (double)pc[4] * cos(3.0 * th) + (double)pc[5] * sin(3.0 * th);
    const double e  = 2.0 * 0.65 / (2.0 * 0.65 - 1.0);     // 13/3
    const double nu = (2.0 * 0.65 - 1.0) * pow(2.0 * 0.65, -e);
    const double kvd = (rho == 0.0) ? 0.0 : nu * pow(rho, e) * exp(-e * g);
    ktab[c * NTAPS + t] = (float)kvd;
}

__global__ __launch_bounds__(256, 8) void frac_dilation_kernel(
    const float* __restrict__ u,
    const float* __restrict__ ktab,    // [32,121] precomputed
    float* __restrict__ out)
{
    __shared__ float klds[NTAPS];
    __shared__ float tile[TH * PITCH];
    __shared__ float wmaxs[4], wmins[4];
    __shared__ int   lohi_lds[KS];

    const int tx  = threadIdx.x;                                   // 0..63
    // block is 64x4: each wave is exactly one ty row -> ty is wave-uniform.
    const int tyS = __builtin_amdgcn_readfirstlane(threadIdx.y);   // scalar 0..3
    const int tid = tyS * 64 + tx;
    const int p   = blockIdx.y;           // plane index b*32+c
    const int c   = p & (NCH - 1);
    const int ox  = blockIdx.x * TX;

    if (tid < NTAPS) klds[tid] = ktab[c * NTAPS + tid];
    // visible after the first __syncthreads below

    const float* uplane = u   + (size_t)p * (HDIM * WDIM);
    float*       oplane = out + (size_t)p * (HDIM * WDIM);
    const int y0 = tyS * VPT;             // this thread's first output row (scalar)

    // ---- per-lane x geometry, computed once (launch-invariant) ----
    const int  gx0    = ox + tx - RR;            // <= 506, only left edge invalid
    const bool m0     = (gx0 >= 0);
    const bool s1lane = (tx < TW - 64);          // lanes 0..9 handle 2nd strip
    const int  gx1    = ox + tx + 64 - RR;
    const bool m1     = s1lane && (gx1 < WDIM);
    const bool xpad   = (ox == 0) || (ox + TX == WDIM);   // block-uniform

    // staging registers: column cc=tx (all lanes) and cc=tx+64 (lanes tx<10)
    float sreg0[NJR], sreg1[NJR];

    // ---- ISSUE: launch global loads for tile itY into sreg (no waits) ----
    auto issue_tile = [&](int itY) {
        const int oyl = itY * TY;
#pragma unroll
        for (int jr = 0; jr < NJR; ++jr) {
            const int r = tyS + 4 * jr;          // scalar
            float v0 = NEGF, v1 = NEGF;
            if (r < TH) {                        // scalar compare
                const int gy = oyl + r - RR;     // scalar
                if (gy >= 0 && gy < HDIM) {      // wave-uniform branch (SALU)
                    const float* row = uplane + (size_t)gy * WDIM;  // s-base
                    if (m0) v0 = row[gx0];       // v-offset load, exec-masked
                    if (m1) v1 = row[gx1];
                }
            }
            sreg0[jr] = v0;
            sreg1[jr] = v1;
        }
    };

    issue_tile(0);   // prologue: loads for first tile in flight

#pragma unroll 1
    for (int itY = 0; itY < HDIM / TY; ++itY) {
        const int oy = itY * TY;

        __syncthreads();   // A: previous compute must finish before tile overwrite

        // ---- WRITE: regs -> LDS, tracking valid-value min/max ----
        float vmax = -3.0e38f, vmin = 3.0e38f;
        const bool clean = !xpad && (itY != 0) && (itY != HDIM / TY - 1);
        if (clean) {
            // no padding anywhere in this tile: select-free tracking
#pragma unroll
            for (int jr = 0; jr < NJR; ++jr) {
                const int r = tyS + 4 * jr;
                if (r < TH) {
                    const float v = sreg0[jr];
                    tile[r * PITCH + tx] = v;
                    vmax = fmaxf(vmax, v);
                    vmin = fminf(vmin, v);
                    if (s1lane) {
                        const float w = sreg1[jr];
                        tile[r * PITCH + tx + 64] = w;
                        vmax = fmaxf(vmax, w);
                        vmin = fminf(vmin, w);
                    }
                }
            }
        } else {
#pragma unroll
            for (int jr = 0; jr < NJR; ++jr) {
                const int r = tyS + 4 * jr;
                if (r < TH) {
                    {
                        const float v = sreg0[jr];
                        tile[r * PITCH + tx] = v;
                        vmax = fmaxf(vmax, v);                          // NEGF never wins
                        vmin = fminf(vmin, (v < -1e29f) ? 3.0e38f : v); // exclude padding
                    }
                    if (s1lane) {
                        const float w = sreg1[jr];
                        tile[r * PITCH + tx + 64] = w;
                        vmax = fmaxf(vmax, w);
                        vmin = fminf(vmin, (w < -1e29f) ? 3.0e38f : w);
                    }
                }
            }
        }
        // wave-level reduce (width 64)
#pragma unroll
        for (int m = 1; m < 64; m <<= 1) {
            vmax = fmaxf(vmax, __shfl_xor(vmax, m, 64));
            vmin = fminf(vmin, __shfl_xor(vmin, m, 64));
        }
        if (tx == 0) { wmaxs[tyS] = vmax; wmins[tyS] = vmin; }
        __syncthreads();   // B: tile + wave partials visible

        const float tmax = fmaxf(fmaxf(wmaxs[0], wmaxs[1]), fmaxf(wmaxs[2], wmaxs[3]));
        const float tmin = fminf(fminf(wmins[0], wmins[1]), fminf(wmins[2], wmins[3]));
        const float delta = tmax - tmin;   // >= 0; center tap k=0 always live

        if (tid < KS) {                    // one thread per dx: contiguous dy hull
            int lo = 1, hi = 0;
#pragma unroll
            for (int dy = 0; dy < KS; ++dy) {
                if (klds[dy * KS + tid] <= delta) { if (lo > hi) lo = dy; hi = dy; }
            }
            lohi_lds[tid] = lo | (hi << 16);
        }
        __syncthreads();   // C: hulls visible

        // ---- issue NEXT tile's loads; latency hides under compute below ----
        if (itY + 1 < HDIM / TY) issue_tile(itY + 1);

        // ---- pruned max-plus accumulation, dy pairs + max3 ----
        float acc[VPT];
#pragma unroll
        for (int i = 0; i < VPT; ++i) acc[i] = NEGF;

#pragma unroll
        for (int dx = 0; dx < KS; ++dx) {
            const int lh = __builtin_amdgcn_readfirstlane(lohi_lds[dx]);
            const int lo = lh & 0xffff;
            const int hi = lh >> 16;

            int dy = lo;
#pragma unroll 1
            for (; dy + 1 <= hi; dy += 2) {
                const float k0 = klds[dy * KS + dx];
                const float k1 = klds[(dy + 1) * KS + dx];
                const float* cp = &tile[(y0 + dy) * PITCH + tx + dx];
                // 9-row shared window for the tap pair (static reg indexing)
                float w[VPT + 1];
#pragma unroll
                for (int r = 0; r < VPT + 1; ++r) w[r] = cp[r * PITCH];
#pragma unroll
                for (int i = 0; i < VPT; ++i)
                    acc[i] = fmaxf(acc[i],
                                   fmaxf(w[i] - k0, w[i + 1] - k1));
            }
            if (dy == hi) {                  // odd tail (wave-uniform)
                const float kvv = klds[dy * KS + dx];
                const float* cp = &tile[(y0 + dy) * PITCH + tx + dx];
#pragma unroll
                for (int i = 0; i < VPT; ++i)
                    acc[i] = fmaxf(acc[i], cp[i * PITCH] - kvv);
            }
        }

        // ---- store ----
#pragma unroll
        for (int i = 0; i < VPT; ++i)
            oplane[(oy + y0 + i) * WDIM + ox + tx] = acc[i];
    }
}

extern "C" void kernel_launch(void* const* d_in, const int* in_sizes, int n_in,
                              void* d_out, int out_size, void* d_ws, size_t ws_size,
                              hipStream_t stream) {
    const float* u  = (const float*)d_in[0];   // (8,32,512,512) fp32
    const float* fp = (const float*)d_in[1];   // (32,6) fp32
    float* out  = (float*)d_out;
    float* ktab = (float*)d_ws;                // 32*121 floats = 15.5 KB scratch

    build_ktab_kernel<<<dim3(NCH), dim3(128), 0, stream>>>(fp, ktab);

    dim3 grid(WDIM / TX, 8 * NCH);   // 8 x-strips, 256 planes
    dim3 block(64, 4);
    frac_dilation_kernel<<<grid, block, 0, stream>>>(u, ktab, out);
}

// Round 5
// 497.740 us; speedup vs baseline: 1.5082x; 1.0289x over previous
//
#include <hip/hip_runtime.h>
#include <math.h>

// FractionalDilationR2: out[b,c,y,x] = max_{dy,dx in [-5,5]} u[b,c,y+dy,x+dx] - k[c,dy+5,dx+5]
// k_c = nu * rho^e * exp(-e * sum_j p[c,j] B_j(theta)),  e = 2a/(2a-1), a = 0.65 (e = 13/3).
//
// Exact pruning: center tap has k=0, so acc >= u[p] >= tileMin. Any tap with
// k >= tileMax - tileMin (valid values only) can never exceed acc -> drop it.
// Per dx column we keep a contiguous [lo,hi] dy-hull of live taps.
//
// R2 (kept): T14 async-STAGE split — 438 -> 397 us.
// R3 (kept): dy-pair + max3, 9-row register window — 397 -> 257 us.
//   Tap math at exact-formulation floor: 1.5 VALU per (tap,output).
// R4 (kept): scalar staging (SALU addressing), clean min/max path — 257 -> 233.
//
// R5 change: TY 32 -> 64 via 8-wave (512-thread) blocks, VPT stays 8. The
// inner pair loop / hull / T14 are byte-identical; only tile geometry changes:
// y-halo 42/32 -> 74/64 (staged rows per output x0.88, FETCH ~292 -> ~260 MB),
// and the per-tile fixed tax (3 barriers, hull, shuffle-reduce, staging issue)
// is paid 8x per plane instead of 16x. LDS 23.1 KB -> 4 blocks/CU x 8 waves
// = 32 waves/CU (same wave count as before).

#define RR 5
#define KS 11
#define NTAPS (KS * KS)     // 121
#define HDIM 512
#define WDIM 512
#define NCH 32
#define TX 64               // output tile width (= lanes in x)
#define TY 64               // output tile height per iteration
#define NWAVES 8            // waves (ty slots) per block
#define VPT 8               // vertical outputs per thread
#define TH (TY + 2 * RR)    // 74 tile rows in LDS
#define TW (TX + 2 * RR)    // 74 tile cols
#define PITCH 76            // padded LDS pitch (floats)
#define NJR 10              // staging row-iters: r = tyS + 8*jr < 74
#define NEGF (-1e30f)

// ---- pre-kernel: build the 32x121 kernel table in double, once per launch ----
__global__ void build_ktab_kernel(const float* __restrict__ finsler,
                                  float* __restrict__ ktab) {
    const int c = blockIdx.x;          // 0..31
    const int t = threadIdx.x;         // 0..127
    if (t >= NTAPS) return;
    const int dy = t / KS - RR;
    const int dx = t % KS - RR;
    const double rho = sqrt((double)(dx * dx + dy * dy));
    const double th  = atan2((double)dy, (double)dx);
    const float* pc = finsler + c * 6;
    const double g =
        (double)pc[0] * cos(th)       + (double)pc[1] * sin(th) +
        (double)pc[2] * cos(2.0 * th) + (double)pc[3] * sin(2.0 * th) +
        (double)pc[4] * cos(3.0 * th) + (double)pc[5] * sin(3.0 * th);
    const double e  = 2.0 * 0.65 / (2.0 * 0.65 - 1.0);     // 13/3
    const double nu = (2.0 * 0.65 - 1.0) * pow(2.0 * 0.65, -e);
    const double kvd = (rho == 0.0) ? 0.0 : nu * pow(rho, e) * exp(-e * g);
    ktab[c * NTAPS + t] = (float)kvd;
}

__global__ __launch_bounds__(512, 8) void frac_dilation_kernel(
    const float* __restrict__ u,
    const float* __restrict__ ktab,    // [32,121] precomputed
    float* __restrict__ out)
{
    __shared__ float klds[NTAPS];
    __shared__ float tile[TH * PITCH];
    __shared__ float wmaxs[NWAVES], wmins[NWAVES];
    __shared__ int   lohi_lds[KS];

    const int tx  = threadIdx.x;                                   // 0..63
    // block is 64x8: each wave is exactly one ty row -> ty is wave-uniform.
    const int tyS = __builtin_amdgcn_readfirstlane(threadIdx.y);   // scalar 0..7
    const int tid = tyS * 64 + tx;
    const int p   = blockIdx.y;           // plane index b*32+c
    const int c   = p & (NCH - 1);
    const int ox  = blockIdx.x * TX;

    if (tid < NTAPS) klds[tid] = ktab[c * NTAPS + tid];
    // visible after the first __syncthreads below

    const float* uplane = u   + (size_t)p * (HDIM * WDIM);
    float*       oplane = out + (size_t)p * (HDIM * WDIM);
    const int y0 = tyS * VPT;             // this thread's first output row (scalar)

    // ---- per-lane x geometry, computed once (launch-invariant) ----
    const int  gx0    = ox + tx - RR;            // <= 506, only left edge invalid
    const bool m0     = (gx0 >= 0);
    const bool s1lane = (tx < TW - 64);          // lanes 0..9 handle 2nd strip
    const int  gx1    = ox + tx + 64 - RR;
    const bool m1     = s1lane && (gx1 < WDIM);
    const bool xpad   = (ox == 0) || (ox + TX == WDIM);   // block-uniform

    // staging registers: column cc=tx (all lanes) and cc=tx+64 (lanes tx<10)
    float sreg0[NJR], sreg1[NJR];

    // ---- ISSUE: launch global loads for tile itY into sreg (no waits) ----
    auto issue_tile = [&](int itY) {
        const int oyl = itY * TY;
#pragma unroll
        for (int jr = 0; jr < NJR; ++jr) {
            const int r = tyS + NWAVES * jr;     // scalar
            float v0 = NEGF, v1 = NEGF;
            if (r < TH) {                        // scalar compare
                const int gy = oyl + r - RR;     // scalar
                if (gy >= 0 && gy < HDIM) {      // wave-uniform branch (SALU)
                    const float* row = uplane + (size_t)gy * WDIM;  // s-base
                    if (m0) v0 = row[gx0];       // v-offset load, exec-masked
                    if (m1) v1 = row[gx1];
                }
            }
            sreg0[jr] = v0;
            sreg1[jr] = v1;
        }
    };

    issue_tile(0);   // prologue: loads for first tile in flight

#pragma unroll 1
    for (int itY = 0; itY < HDIM / TY; ++itY) {
        const int oy = itY * TY;

        __syncthreads();   // A: previous compute must finish before tile overwrite

        // ---- WRITE: regs -> LDS, tracking valid-value min/max ----
        float vmax = -3.0e38f, vmin = 3.0e38f;
        const bool clean = !xpad && (itY != 0) && (itY != HDIM / TY - 1);
        if (clean) {
            // no padding anywhere in this tile: select-free tracking
#pragma unroll
            for (int jr = 0; jr < NJR; ++jr) {
                const int r = tyS + NWAVES * jr;
                if (r < TH) {
                    const float v = sreg0[jr];
                    tile[r * PITCH + tx] = v;
                    vmax = fmaxf(vmax, v);
                    vmin = fminf(vmin, v);
                    if (s1lane) {
                        const float w = sreg1[jr];
                        tile[r * PITCH + tx + 64] = w;
                        vmax = fmaxf(vmax, w);
                        vmin = fminf(vmin, w);
                    }
                }
            }
        } else {
#pragma unroll
            for (int jr = 0; jr < NJR; ++jr) {
                const int r = tyS + NWAVES * jr;
                if (r < TH) {
                    {
                        const float v = sreg0[jr];
                        tile[r * PITCH + tx] = v;
                        vmax = fmaxf(vmax, v);                          // NEGF never wins
                        vmin = fminf(vmin, (v < -1e29f) ? 3.0e38f : v); // exclude padding
                    }
                    if (s1lane) {
                        const float w = sreg1[jr];
                        tile[r * PITCH + tx + 64] = w;
                        vmax = fmaxf(vmax, w);
                        vmin = fminf(vmin, (w < -1e29f) ? 3.0e38f : w);
                    }
                }
            }
        }
        // wave-level reduce (width 64)
#pragma unroll
        for (int m = 1; m < 64; m <<= 1) {
            vmax = fmaxf(vmax, __shfl_xor(vmax, m, 64));
            vmin = fminf(vmin, __shfl_xor(vmin, m, 64));
        }
        if (tx == 0) { wmaxs[tyS] = vmax; wmins[tyS] = vmin; }
        __syncthreads();   // B: tile + wave partials visible

        float tmax = wmaxs[0], tmin = wmins[0];
#pragma unroll
        for (int wv = 1; wv < NWAVES; ++wv) {
            tmax = fmaxf(tmax, wmaxs[wv]);
            tmin = fminf(tmin, wmins[wv]);
        }
        const float delta = tmax - tmin;   // >= 0; center tap k=0 always live

        if (tid < KS) {                    // one thread per dx: contiguous dy hull
            int lo = 1, hi = 0;
#pragma unroll
            for (int dy = 0; dy < KS; ++dy) {
                if (klds[dy * KS + tid] <= delta) { if (lo > hi) lo = dy; hi = dy; }
            }
            lohi_lds[tid] = lo | (hi << 16);
        }
        __syncthreads();   // C: hulls visible

        // ---- issue NEXT tile's loads; latency hides under compute below ----
        if (itY + 1 < HDIM / TY) issue_tile(itY + 1);

        // ---- pruned max-plus accumulation, dy pairs + max3 ----
        float acc[VPT];
#pragma unroll
        for (int i = 0; i < VPT; ++i) acc[i] = NEGF;

#pragma unroll
        for (int dx = 0; dx < KS; ++dx) {
            const int lh = __builtin_amdgcn_readfirstlane(lohi_lds[dx]);
            const int lo = lh & 0xffff;
            const int hi = lh >> 16;

            int dy = lo;
#pragma unroll 1
            for (; dy + 1 <= hi; dy += 2) {
                const float k0 = klds[dy * KS + dx];
                const float k1 = klds[(dy + 1) * KS + dx];
                const float* cp = &tile[(y0 + dy) * PITCH + tx + dx];
                // 9-row shared window for the tap pair (static reg indexing)
                float w[VPT + 1];
#pragma unroll
                for (int r = 0; r < VPT + 1; ++r) w[r] = cp[r * PITCH];
#pragma unroll
                for (int i = 0; i < VPT; ++i)
                    acc[i] = fmaxf(acc[i],
                                   fmaxf(w[i] - k0, w[i + 1] - k1));
            }
            if (dy == hi) {                  // odd tail (wave-uniform)
                const float kvv = klds[dy * KS + dx];
                const float* cp = &tile[(y0 + dy) * PITCH + tx + dx];
#pragma unroll
                for (int i = 0; i < VPT; ++i)
                    acc[i] = fmaxf(acc[i], cp[i * PITCH] - kvv);
            }
        }

        // ---- store ----
#pragma unroll
        for (int i = 0; i < VPT; ++i)
            oplane[(oy + y0 + i) * WDIM + ox + tx] = acc[i];
    }
}

extern "C" void kernel_launch(void* const* d_in, const int* in_sizes, int n_in,
                              void* d_out, int out_size, void* d_ws, size_t ws_size,
                              hipStream_t stream) {
    const float* u  = (const float*)d_in[0];   // (8,32,512,512) fp32
    const float* fp = (const float*)d_in[1];   // (32,6) fp32
    float* out  = (float*)d_out;
    float* ktab = (float*)d_ws;                // 32*121 floats = 15.5 KB scratch

    build_ktab_kernel<<<dim3(NCH), dim3(128), 0, stream>>>(fp, ktab);

    dim3 grid(WDIM / TX, 8 * NCH);   // 8 x-strips, 256 planes
    dim3 block(64, NWAVES);
    frac_dilation_kernel<<<grid, block, 0, stream>>>(u, ktab, out);
}